// Round 1
// baseline (313.992 us; speedup 1.0000x reference)
//
#include <hip/hip_runtime.h>
#include <hip/hip_bf16.h>

#define NNODES 2048
#define NHEAD 8
#define DKDIM 64

// ---------------- CSR build kernels ----------------

__global__ void hist_kernel(const int* __restrict__ dst, int* __restrict__ counts, int E) {
    int i = blockIdx.x * blockDim.x + threadIdx.x;
    if (i < E) atomicAdd(&counts[dst[i]], 1);
}

// single block, 256 threads, N = 2048 (8 elements per thread)
__global__ void scan_kernel(const int* __restrict__ counts, int* __restrict__ offsets,
                            int* __restrict__ cursor) {
    int t = threadIdx.x;
    int local[8];
    int sum = 0;
#pragma unroll
    for (int i = 0; i < 8; ++i) { local[i] = counts[t * 8 + i]; sum += local[i]; }

    int lane = t & 63, wid = t >> 6;
    int x = sum;
#pragma unroll
    for (int d = 1; d < 64; d <<= 1) {
        int y = __shfl_up(x, d);
        if (lane >= d) x += y;
    }
    __shared__ int wsum[4];
    if (lane == 63) wsum[wid] = x;
    __syncthreads();
    int wbase = 0;
    for (int w = 0; w < wid; ++w) wbase += wsum[w];
    int excl = wbase + x - sum;  // exclusive prefix for this thread's 8 elements
    int run = excl;
#pragma unroll
    for (int i = 0; i < 8; ++i) {
        offsets[t * 8 + i] = run;
        cursor[t * 8 + i] = run;
        run += local[i];
    }
    if (t == 255) offsets[NNODES] = run;
}

__global__ void scatter_kernel(const int* __restrict__ srcA, const int* __restrict__ dstA,
                               int* __restrict__ cursor, int* __restrict__ src_sorted, int E) {
    int i = blockIdx.x * blockDim.x + threadIdx.x;
    if (i < E) {
        int pos = atomicAdd(&cursor[dstA[i]], 1);
        src_sorted[pos] = srcA[i];
    }
}

// ---------------- main attention kernel ----------------
// One block per destination node. 256 threads = 4 waves.
// Wave w handles heads 2w and 2w+1 (lane>>5 selects which).
// Lane owns float2 slice d = {2*(lane&31), 2*(lane&31)+1} of DK=64.
__global__ void __launch_bounds__(256, 8) attn_kernel(
    const float* __restrict__ q, const float* __restrict__ k, const float* __restrict__ v,
    const int* __restrict__ offsets, const int* __restrict__ src_sorted,
    float* __restrict__ out) {
    int node = blockIdx.x;
    int t = threadIdx.x;
    int wave = t >> 6;
    int lane = t & 63;
    int h = (wave << 1) | (lane >> 5);   // 0..7
    int dpair = lane & 31;               // float2 index within head dim

    const float2* kb = (const float2*)k;
    const float2* vb = (const float2*)v;
    float2 qv = ((const float2*)q)[((size_t)node * NHEAD + h) * (DKDIM / 2) + dpair];

    int beg = offsets[node];
    int end = offsets[node + 1];

    float acc0 = 0.f, acc1 = 0.f, zacc = 0.f;

    for (int e = beg; e < end; ++e) {
        int src = src_sorted[e];
        size_t base = ((size_t)src * NHEAD + h) * (DKDIM / 2) + dpair;
        float2 kv = kb[base];
        float2 vv = vb[base];
        float p = kv.x * qv.x + kv.y * qv.y;
        // butterfly reduce across the 32-lane head group
        p += __shfl_xor(p, 1);
        p += __shfl_xor(p, 2);
        p += __shfl_xor(p, 4);
        p += __shfl_xor(p, 8);
        p += __shfl_xor(p, 16);
        float sc = p * 0.125f;                       // / sqrt(64)
        sc = fminf(fmaxf(sc, -10.f), 10.f);
        float s = __expf(sc);
        acc0 = fmaf(s, vv.x, acc0);
        acc1 = fmaf(s, vv.y, acc1);
        zacc += s;
    }

    float inv = 1.0f / zacc;
    float2 o;
    o.x = acc0 * inv;
    o.y = acc1 * inv;
    ((float2*)out)[((size_t)node * NHEAD + h) * (DKDIM / 2) + dpair] = o;
}

// ---------------- launch ----------------

extern "C" void kernel_launch(void* const* d_in, const int* in_sizes, int n_in,
                              void* d_out, int out_size, void* d_ws, size_t ws_size,
                              hipStream_t stream) {
    const float* q = (const float*)d_in[0];
    const float* k = (const float*)d_in[1];
    const float* v = (const float*)d_in[2];
    const int* esrc = (const int*)d_in[3];
    const int* edst = (const int*)d_in[4];
    float* out = (float*)d_out;

    const int E = in_sizes[3];
    const int N = NNODES;

    int* counts = (int*)d_ws;            // N
    int* offsets = counts + N;           // N+1
    int* cursor = offsets + N + 1;       // N
    int* src_sorted = cursor + N;        // E

    hipMemsetAsync(counts, 0, N * sizeof(int), stream);
    hist_kernel<<<(E + 255) / 256, 256, 0, stream>>>(edst, counts, E);
    scan_kernel<<<1, 256, 0, stream>>>(counts, offsets, cursor);
    scatter_kernel<<<(E + 255) / 256, 256, 0, stream>>>(esrc, edst, cursor, src_sorted, E);
    attn_kernel<<<N, 256, 0, stream>>>(q, k, v, offsets, src_sorted, out);
}